// Round 1
// baseline (424.896 us; speedup 1.0000x reference)
//
#include <hip/hip_runtime.h>
#include <cstdint>

// Problem: B=4, S=2048, D_MODEL=1024, H=16, depth=64.
// Pipeline: pack x->bf16; pack/transpose W->bf16 [N][K]; QKV GEMM (bf16 MFMA,
// fp32 acc) -> Q[bh,s,d], K[bh,s,d], Vt[bh,d,s]; flash attention; out GEMM -> fp32.

typedef __bf16 bf16x8 __attribute__((ext_vector_type(8)));
typedef float f32x4 __attribute__((ext_vector_type(4)));

#define CEXP 0.18033688011112042f  // (1/8) * log2(e)

__device__ __forceinline__ unsigned short f2bf(float f) {
  union { float f; unsigned int u; } v; v.f = f;
  unsigned int r = v.u + 0x7FFFu + ((v.u >> 16) & 1u);  // RNE
  return (unsigned short)(r >> 16);
}

// async global->LDS, 16B per lane. LDS dest = wave-uniform base + lane*16.
__device__ __forceinline__ void gl_lds16(const void* g, void* l) {
  __builtin_amdgcn_global_load_lds(
      (const __attribute__((address_space(1))) void*)(unsigned long long)g,
      (__attribute__((address_space(3))) void*)(unsigned int)(unsigned long long)l,
      16, 0, 0);
}

// ---------------- pack x (fp32 -> bf16) ----------------
__global__ __launch_bounds__(256) void pack_x_kernel(const float* __restrict__ x,
                                                     unsigned short* __restrict__ xb) {
  int i = (blockIdx.x * 256 + threadIdx.x) * 4;
  float4 v = *(const float4*)(x + i);
  unsigned int lo = (unsigned int)f2bf(v.x) | ((unsigned int)f2bf(v.y) << 16);
  unsigned int hi = (unsigned int)f2bf(v.z) | ((unsigned int)f2bf(v.w) << 16);
  uint2 st; st.x = lo; st.y = hi;
  *(uint2*)(xb + i) = st;
}

// ---------------- pack + transpose weights: Wt[n][k] = w[k][n], bf16 ----------------
__global__ __launch_bounds__(256) void pack_w_kernel(const float* __restrict__ wq,
                                                     const float* __restrict__ wk,
                                                     const float* __restrict__ wv,
                                                     const float* __restrict__ wo,
                                                     unsigned short* __restrict__ wqkvt,
                                                     unsigned short* __restrict__ wot) {
  __shared__ unsigned short T[64 * 66];  // +2 pad: conflict-free
  int mat = blockIdx.x >> 8;             // 0..3 = wq,wk,wv,wo
  int tile = blockIdx.x & 255;
  int tk = tile >> 4, tn = tile & 15;    // 64x64 tiles
  const float* W = (mat == 0) ? wq : (mat == 1) ? wk : (mat == 2) ? wv : wo;
  int t = threadIdx.x;
#pragma unroll
  for (int p = 0; p < 16; ++p) {
    int e = p * 256 + t;
    int r = e >> 6, c = e & 63;
    T[c * 66 + r] = f2bf(W[(tk * 64 + r) * 1024 + tn * 64 + c]);
  }
  __syncthreads();
  unsigned short* dst = (mat < 3) ? (wqkvt + mat * 1024 * 1024) : wot;
#pragma unroll
  for (int p = 0; p < 16; ++p) {
    int e = p * 256 + t;
    int nn = e >> 6, kk = e & 63;
    dst[(tn * 64 + nn) * 1024 + tk * 64 + kk] = T[nn * 66 + kk];
  }
}

// ---------------- GEMM: C[M][N] = A[M][1024] * Bt[N][1024]^T ----------------
// MODE 0: QKV epilogue (bias + scatter bf16 to Q/K/Vt).  MODE 1: fp32 out + bias.
template <int MODE>
__global__ __launch_bounds__(256) void gemm_bt_kernel(
    const unsigned short* __restrict__ A, const unsigned short* __restrict__ Bt,
    const float* __restrict__ b0, const float* __restrict__ b1, const float* __restrict__ b2,
    unsigned short* __restrict__ Qg, unsigned short* __restrict__ Kg,
    unsigned short* __restrict__ Vtg, float* __restrict__ Of) {
  __shared__ __align__(16) unsigned short As[128 * 64];  // XOR-swizzled rows
  __shared__ __align__(16) unsigned short Bs[128 * 64];
  const int t = threadIdx.x;
  const int lane = t & 63, wave = t >> 6;
  const int l15 = lane & 15, quad = lane >> 4;
  const int wm = wave & 1, wn = wave >> 1;
  const int m0 = blockIdx.x * 128, n0 = blockIdx.y * 128;

  f32x4 acc[4][4];
#pragma unroll
  for (int i = 0; i < 4; ++i)
#pragma unroll
    for (int j = 0; j < 4; ++j) acc[i][j] = (f32x4){0.f, 0.f, 0.f, 0.f};

  // swizzled fragment byte-chunk offsets (elements): chunk = (kc*4+quad) ^ (row&7)
  const int Xo0 = ((quad ^ (l15 & 7)) * 8);
  const int Xo1 = (((4 + quad) ^ (l15 & 7)) * 8);

  for (int k0 = 0; k0 < 1024; k0 += 64) {
    __syncthreads();
#pragma unroll
    for (int p = 0; p < 4; ++p) {
      int s = p * 256 + t;
      int row = s >> 3;
      int cc = (s & 7) ^ (row & 7);
      gl_lds16(A + (m0 + row) * 1024 + k0 + cc * 8, (void*)(As + (p * 256 + wave * 64) * 8));
      gl_lds16(Bt + (n0 + row) * 1024 + k0 + cc * 8, (void*)(Bs + (p * 256 + wave * 64) * 8));
    }
    __syncthreads();
#pragma unroll
    for (int kc = 0; kc < 2; ++kc) {
      const int Xo = kc ? Xo1 : Xo0;
      bf16x8 af[4], bfr[4];
#pragma unroll
      for (int mi = 0; mi < 4; ++mi)
        af[mi] = *(const bf16x8*)&As[(wm * 64 + mi * 16 + l15) * 64 + Xo];
#pragma unroll
      for (int ni = 0; ni < 4; ++ni)
        bfr[ni] = *(const bf16x8*)&Bs[(wn * 64 + ni * 16 + l15) * 64 + Xo];
#pragma unroll
      for (int mi = 0; mi < 4; ++mi)
#pragma unroll
        for (int ni = 0; ni < 4; ++ni)
          acc[mi][ni] = __builtin_amdgcn_mfma_f32_16x16x32_bf16(af[mi], bfr[ni], acc[mi][ni], 0, 0, 0);
    }
  }

  if (MODE == 0) {
    const int seg = blockIdx.y >> 3;  // 0=Q,1=K,2=V (N blocks of 128; 8 per segment)
    const float* bias = (seg == 0) ? b0 : (seg == 1) ? b1 : b2;
    unsigned short* qk = (seg == 0) ? Qg : Kg;
#pragma unroll
    for (int mi = 0; mi < 4; ++mi)
#pragma unroll
      for (int ni = 0; ni < 4; ++ni) {
        int n = n0 + wn * 64 + ni * 16 + l15;
        int nn = n & 1023;
        float bb = bias[nn];
        int h = nn >> 6, d = nn & 63;
#pragma unroll
        for (int r = 0; r < 4; ++r) {
          int m = m0 + wm * 64 + mi * 16 + quad * 4 + r;
          int b = m >> 11, s = m & 2047;
          unsigned short ob = f2bf(acc[mi][ni][r] + bb);
          if (seg == 2)
            Vtg[((b * 16 + h) * 64 + d) * 2048 + s] = ob;      // V transposed [bh][d][s]
          else
            qk[((b * 16 + h) * 2048 + s) * 64 + d] = ob;       // [bh][s][d]
        }
      }
  } else {
#pragma unroll
    for (int mi = 0; mi < 4; ++mi)
#pragma unroll
      for (int ni = 0; ni < 4; ++ni) {
        int n = n0 + wn * 64 + ni * 16 + l15;
        float bb = b0[n];
#pragma unroll
        for (int r = 0; r < 4; ++r) {
          int m = m0 + wm * 64 + mi * 16 + quad * 4 + r;
          Of[m * 1024 + n] = acc[mi][ni][r] + bb;
        }
      }
  }
}

// ---------------- flash attention ----------------
// grid: 1024 blocks = 64 (b*h) x 16 q-tiles of 128. 4 waves; wave owns 32 q rows.
__global__ __launch_bounds__(256) void attn_kernel(const unsigned short* __restrict__ Qg,
                                                   const unsigned short* __restrict__ Kg,
                                                   const unsigned short* __restrict__ Vtg,
                                                   unsigned short* __restrict__ Og) {
  __shared__ __align__(16) unsigned short Qs[128 * 64];  // swizzled
  __shared__ __align__(16) unsigned short Ks[64 * 64];   // swizzled
  __shared__ __align__(16) unsigned short Vts[64 * 64];  // [d][key], swizzled
  __shared__ __align__(16) unsigned short Ps[128 * 72];  // padded rows (+8)

  const int t = threadIdx.x;
  const int lane = t & 63, wave = t >> 6;
  const int l15 = lane & 15, quad = lane >> 4;
  const int bh = blockIdx.x >> 4, qt = blockIdx.x & 15;

  const unsigned short* Qh = Qg + (bh * 2048 + qt * 128) * 64;
  const unsigned short* Kh = Kg + bh * 2048 * 64;
  const unsigned short* Vth = Vtg + bh * 64 * 2048;

  // stage Q tile once
#pragma unroll
  for (int p = 0; p < 4; ++p) {
    int s = p * 256 + t;
    int row = s >> 3, cc = (s & 7) ^ (row & 7);
    gl_lds16(Qh + row * 64 + cc * 8, (void*)(Qs + (p * 256 + wave * 64) * 8));
  }

  float mrow[2][4], lrow[2][4];
  f32x4 oacc[2][4];
#pragma unroll
  for (int mi = 0; mi < 2; ++mi)
#pragma unroll
    for (int r = 0; r < 4; ++r) { mrow[mi][r] = -1e30f; lrow[mi][r] = 0.f; }
#pragma unroll
  for (int mi = 0; mi < 2; ++mi)
#pragma unroll
    for (int ni = 0; ni < 4; ++ni) oacc[mi][ni] = (f32x4){0.f, 0.f, 0.f, 0.f};

  const int Xo0 = ((quad ^ (l15 & 7)) * 8);
  const int Xo1 = (((4 + quad) ^ (l15 & 7)) * 8);

  for (int kt = 0; kt < 32; ++kt) {
    __syncthreads();  // protect LDS reuse (also drains Q stage on kt=0)
#pragma unroll
    for (int p = 0; p < 2; ++p) {
      int s = p * 256 + t;
      int row = s >> 3, cc = (s & 7) ^ (row & 7);
      gl_lds16(Kh + (kt * 64 + row) * 64 + cc * 8, (void*)(Ks + (p * 256 + wave * 64) * 8));
      gl_lds16(Vth + row * 2048 + kt * 64 + cc * 8, (void*)(Vts + (p * 256 + wave * 64) * 8));
    }
    __syncthreads();

    // S = Q K^T  (per wave: 32 q rows x 64 keys)
    f32x4 sacc[2][4];
#pragma unroll
    for (int mi = 0; mi < 2; ++mi)
#pragma unroll
      for (int ni = 0; ni < 4; ++ni) sacc[mi][ni] = (f32x4){0.f, 0.f, 0.f, 0.f};
#pragma unroll
    for (int kc = 0; kc < 2; ++kc) {
      const int Xo = kc ? Xo1 : Xo0;
      bf16x8 aq[2], bk[4];
#pragma unroll
      for (int mi = 0; mi < 2; ++mi)
        aq[mi] = *(const bf16x8*)&Qs[(wave * 32 + mi * 16 + l15) * 64 + Xo];
#pragma unroll
      for (int ni = 0; ni < 4; ++ni)
        bk[ni] = *(const bf16x8*)&Ks[(ni * 16 + l15) * 64 + Xo];
#pragma unroll
      for (int mi = 0; mi < 2; ++mi)
#pragma unroll
        for (int ni = 0; ni < 4; ++ni)
          sacc[mi][ni] = __builtin_amdgcn_mfma_f32_16x16x32_bf16(aq[mi], bk[ni], sacc[mi][ni], 0, 0, 0);
    }

    // online softmax (scale 1/8 folded into CEXP); P -> LDS (own rows only)
#pragma unroll
    for (int mi = 0; mi < 2; ++mi) {
#pragma unroll
      for (int r = 0; r < 4; ++r) {
        float mx = fmaxf(fmaxf(sacc[mi][0][r], sacc[mi][1][r]),
                         fmaxf(sacc[mi][2][r], sacc[mi][3][r]));
        mx = fmaxf(mx, __shfl_xor(mx, 1));
        mx = fmaxf(mx, __shfl_xor(mx, 2));
        mx = fmaxf(mx, __shfl_xor(mx, 4));
        mx = fmaxf(mx, __shfl_xor(mx, 8));
        float mold = mrow[mi][r];
        float mnew = fmaxf(mold, mx);
        float alpha = __builtin_amdgcn_exp2f((mold - mnew) * CEXP);
        float p0 = __builtin_amdgcn_exp2f((sacc[mi][0][r] - mnew) * CEXP);
        float p1 = __builtin_amdgcn_exp2f((sacc[mi][1][r] - mnew) * CEXP);
        float p2 = __builtin_amdgcn_exp2f((sacc[mi][2][r] - mnew) * CEXP);
        float p3 = __builtin_amdgcn_exp2f((sacc[mi][3][r] - mnew) * CEXP);
        float sum = (p0 + p1) + (p2 + p3);
        sum += __shfl_xor(sum, 1);
        sum += __shfl_xor(sum, 2);
        sum += __shfl_xor(sum, 4);
        sum += __shfl_xor(sum, 8);
        lrow[mi][r] = lrow[mi][r] * alpha + sum;
        mrow[mi][r] = mnew;
#pragma unroll
        for (int ni = 0; ni < 4; ++ni) oacc[mi][ni][r] *= alpha;
        int prow = wave * 32 + mi * 16 + quad * 4 + r;
        Ps[prow * 72 + 0 + l15] = f2bf(p0);
        Ps[prow * 72 + 16 + l15] = f2bf(p1);
        Ps[prow * 72 + 32 + l15] = f2bf(p2);
        Ps[prow * 72 + 48 + l15] = f2bf(p3);
      }
    }

    // O += P V  (A = P from own LDS rows; B = V^T tile, contiguous)
#pragma unroll
    for (int kc = 0; kc < 2; ++kc) {
      const int Xo = kc ? Xo1 : Xo0;
      bf16x8 ap[2], bv[4];
#pragma unroll
      for (int mi = 0; mi < 2; ++mi)
        ap[mi] = *(const bf16x8*)&Ps[(wave * 32 + mi * 16 + l15) * 72 + kc * 32 + quad * 8];
#pragma unroll
      for (int ni = 0; ni < 4; ++ni)
        bv[ni] = *(const bf16x8*)&Vts[(ni * 16 + l15) * 64 + Xo];
#pragma unroll
      for (int mi = 0; mi < 2; ++mi)
#pragma unroll
        for (int ni = 0; ni < 4; ++ni)
          oacc[mi][ni] = __builtin_amdgcn_mfma_f32_16x16x32_bf16(ap[mi], bv[ni], oacc[mi][ni], 0, 0, 0);
    }
  }

  // epilogue: O / l -> Og[b*2048+q][h*64+d] (bf16)
  const int b = bh >> 4, h = bh & 15;
#pragma unroll
  for (int mi = 0; mi < 2; ++mi) {
    float inv[4];
#pragma unroll
    for (int r = 0; r < 4; ++r) inv[r] = 1.f / lrow[mi][r];
#pragma unroll
    for (int ni = 0; ni < 4; ++ni)
#pragma unroll
      for (int r = 0; r < 4; ++r) {
        int q = qt * 128 + wave * 32 + mi * 16 + quad * 4 + r;
        Og[(b * 2048 + q) * 1024 + h * 64 + ni * 16 + l15] = f2bf(oacc[mi][ni][r] * inv[r]);
      }
  }
}

extern "C" void kernel_launch(void* const* d_in, const int* in_sizes, int n_in,
                              void* d_out, int out_size, void* d_ws, size_t ws_size,
                              hipStream_t stream) {
  const float* x  = (const float*)d_in[0];
  const float* wq = (const float*)d_in[1];
  const float* bq = (const float*)d_in[2];
  const float* wk = (const float*)d_in[3];
  const float* bk = (const float*)d_in[4];
  const float* wv = (const float*)d_in[5];
  const float* bv = (const float*)d_in[6];
  const float* wo = (const float*)d_in[7];
  const float* bo = (const float*)d_in[8];
  char* ws = (char*)d_ws;
  // workspace layout (88 MB total)
  unsigned short* Xb    = (unsigned short*)(ws);                      // 16 MB
  unsigned short* Wqkvt = (unsigned short*)(ws + (16ull << 20));      // 6 MB
  unsigned short* Wot   = (unsigned short*)(ws + (22ull << 20));      // 2 MB
  unsigned short* Qg    = (unsigned short*)(ws + (24ull << 20));      // 16 MB
  unsigned short* Kg    = (unsigned short*)(ws + (40ull << 20));      // 16 MB
  unsigned short* Vtg   = (unsigned short*)(ws + (56ull << 20));      // 16 MB
  unsigned short* Og    = (unsigned short*)(ws + (72ull << 20));      // 16 MB

  pack_x_kernel<<<8192, 256, 0, stream>>>(x, Xb);
  pack_w_kernel<<<1024, 256, 0, stream>>>(wq, wk, wv, wo, Wqkvt, Wot);
  gemm_bt_kernel<0><<<dim3(64, 24), 256, 0, stream>>>(Xb, Wqkvt, bq, bk, bv,
                                                      Qg, Kg, Vtg, nullptr);
  attn_kernel<<<1024, 256, 0, stream>>>(Qg, Kg, Vtg, Og);
  gemm_bt_kernel<1><<<dim3(64, 8), 256, 0, stream>>>(Og, Wot, bo, nullptr, nullptr,
                                                     nullptr, nullptr, nullptr,
                                                     (float*)d_out);
}

// Round 2
// 292.712 us; speedup vs baseline: 1.4516x; 1.4516x over previous
//
#include <hip/hip_runtime.h>
#include <cstdint>

// Problem: B=4, S=2048, D_MODEL=1024, H=16, depth=64.
// Pipeline: pack x->bf16; pack/transpose W->bf16 [N][K]; QKV GEMM (bf16 MFMA,
// fp32 acc) -> Q[bh,s,d] (pre-scaled by log2e/8), K[bh,s,d], Vt[bh,d,s'] with
// key order permuted within 64-blocks; flash attention (no-max softmax, P stays
// in registers); out GEMM -> fp32.

typedef __bf16 bf16x8 __attribute__((ext_vector_type(8)));
typedef float f32x4 __attribute__((ext_vector_type(4)));
typedef int i32x4 __attribute__((ext_vector_type(4)));

#define CEXP 0.18033688011112042f  // (1/8) * log2(e), folded into Q

__device__ __forceinline__ unsigned short f2bf(float f) {
  union { float f; unsigned int u; } v; v.f = f;
  unsigned int r = v.u + 0x7FFFu + ((v.u >> 16) & 1u);  // RNE
  return (unsigned short)(r >> 16);
}
__device__ __forceinline__ unsigned int fbits(float f) {
  union { float f; unsigned int u; } v; v.f = f; return v.u;
}

// async global->LDS, 16B per lane. LDS dest = wave-uniform base + lane*16.
__device__ __forceinline__ void gl_lds16(const void* g, void* l) {
  __builtin_amdgcn_global_load_lds(
      (const __attribute__((address_space(1))) void*)(unsigned long long)g,
      (__attribute__((address_space(3))) void*)(unsigned int)(unsigned long long)l,
      16, 0, 0);
}

// ---------------- pack x (fp32 -> bf16) ----------------
__global__ __launch_bounds__(256) void pack_x_kernel(const float* __restrict__ x,
                                                     unsigned short* __restrict__ xb) {
  int i = (blockIdx.x * 256 + threadIdx.x) * 4;
  float4 v = *(const float4*)(x + i);
  unsigned int lo = (unsigned int)f2bf(v.x) | ((unsigned int)f2bf(v.y) << 16);
  unsigned int hi = (unsigned int)f2bf(v.z) | ((unsigned int)f2bf(v.w) << 16);
  uint2 st; st.x = lo; st.y = hi;
  *(uint2*)(xb + i) = st;
}

// ---------------- pack + transpose weights: Wt[n][k] = w[k][n], bf16 ----------------
__global__ __launch_bounds__(256) void pack_w_kernel(const float* __restrict__ wq,
                                                     const float* __restrict__ wk,
                                                     const float* __restrict__ wv,
                                                     const float* __restrict__ wo,
                                                     unsigned short* __restrict__ wqkvt,
                                                     unsigned short* __restrict__ wot) {
  __shared__ unsigned short T[64 * 66];  // +2 pad: conflict-free
  int mat = blockIdx.x >> 8;             // 0..3 = wq,wk,wv,wo
  int tile = blockIdx.x & 255;
  int tk = tile >> 4, tn = tile & 15;    // 64x64 tiles
  const float* W = (mat == 0) ? wq : (mat == 1) ? wk : (mat == 2) ? wv : wo;
  int t = threadIdx.x;
#pragma unroll
  for (int p = 0; p < 16; ++p) {
    int e = p * 256 + t;
    int r = e >> 6, c = e & 63;
    T[c * 66 + r] = f2bf(W[(tk * 64 + r) * 1024 + tn * 64 + c]);
  }
  __syncthreads();
  unsigned short* dst = (mat < 3) ? (wqkvt + mat * 1024 * 1024) : wot;
#pragma unroll
  for (int p = 0; p < 16; ++p) {
    int e = p * 256 + t;
    int nn = e >> 6, kk = e & 63;
    dst[(tn * 64 + nn) * 1024 + tk * 64 + kk] = T[nn * 66 + kk];
  }
}

// ---------------- GEMM: C[M][N] = A[M][1024] * Bt[N][1024]^T ----------------
// MODE 0: QKV epilogue (bias + scatter bf16 to Q/K/Vt; Q pre-scaled by CEXP;
//         Vt key order permuted within 64-blocks).  MODE 1: fp32 out + bias.
template <int MODE>
__global__ __launch_bounds__(256) void gemm_bt_kernel(
    const unsigned short* __restrict__ A, const unsigned short* __restrict__ Bt,
    const float* __restrict__ b0, const float* __restrict__ b1, const float* __restrict__ b2,
    unsigned short* __restrict__ Qg, unsigned short* __restrict__ Kg,
    unsigned short* __restrict__ Vtg, float* __restrict__ Of) {
  __shared__ __align__(16) unsigned short As[128 * 64];  // XOR-swizzled rows
  __shared__ __align__(16) unsigned short Bs[128 * 64];
  const int t = threadIdx.x;
  const int lane = t & 63, wave = t >> 6;
  const int l15 = lane & 15, quad = lane >> 4;
  const int wm = wave & 1, wn = wave >> 1;
  const int m0 = blockIdx.x * 128, n0 = blockIdx.y * 128;

  f32x4 acc[4][4];
#pragma unroll
  for (int i = 0; i < 4; ++i)
#pragma unroll
    for (int j = 0; j < 4; ++j) acc[i][j] = (f32x4){0.f, 0.f, 0.f, 0.f};

  const int Xo0 = ((quad ^ (l15 & 7)) * 8);
  const int Xo1 = (((4 + quad) ^ (l15 & 7)) * 8);

  for (int k0 = 0; k0 < 1024; k0 += 64) {
    __syncthreads();
#pragma unroll
    for (int p = 0; p < 4; ++p) {
      int s = p * 256 + t;
      int row = s >> 3;
      int cc = (s & 7) ^ (row & 7);
      gl_lds16(A + (m0 + row) * 1024 + k0 + cc * 8, (void*)(As + (p * 256 + wave * 64) * 8));
      gl_lds16(Bt + (n0 + row) * 1024 + k0 + cc * 8, (void*)(Bs + (p * 256 + wave * 64) * 8));
    }
    __syncthreads();
#pragma unroll
    for (int kc = 0; kc < 2; ++kc) {
      const int Xo = kc ? Xo1 : Xo0;
      bf16x8 af[4], bfr[4];
#pragma unroll
      for (int mi = 0; mi < 4; ++mi)
        af[mi] = *(const bf16x8*)&As[(wm * 64 + mi * 16 + l15) * 64 + Xo];
#pragma unroll
      for (int ni = 0; ni < 4; ++ni)
        bfr[ni] = *(const bf16x8*)&Bs[(wn * 64 + ni * 16 + l15) * 64 + Xo];
#pragma unroll
      for (int mi = 0; mi < 4; ++mi)
#pragma unroll
        for (int ni = 0; ni < 4; ++ni)
          acc[mi][ni] = __builtin_amdgcn_mfma_f32_16x16x32_bf16(af[mi], bfr[ni], acc[mi][ni], 0, 0, 0);
    }
  }

  if (MODE == 0) {
    const int seg = blockIdx.y >> 3;  // 0=Q,1=K,2=V
    const float* bias = (seg == 0) ? b0 : (seg == 1) ? b1 : b2;
    unsigned short* qk = (seg == 0) ? Qg : Kg;
#pragma unroll
    for (int mi = 0; mi < 4; ++mi)
#pragma unroll
      for (int ni = 0; ni < 4; ++ni) {
        int n = n0 + wn * 64 + ni * 16 + l15;
        int nn = n & 1023;
        float bb = bias[nn];
        int h = nn >> 6, d = nn & 63;
#pragma unroll
        for (int r = 0; r < 4; ++r) {
          int m = m0 + wm * 64 + mi * 16 + quad * 4 + r;
          int b = m >> 11, s = m & 2047;
          float val = acc[mi][ni][r] + bb;
          if (seg == 2) {
            // permute key order within 64-blocks so attn's P-register order
            // matches V^T's staged order: pos = kc<<5 | q<<3 | u<<2 | r
            int sp = (s & ~63) | (s & 32) | ((s & 12) << 1) | ((s & 16) >> 2) | (s & 3);
            Vtg[((b * 16 + h) * 64 + d) * 2048 + sp] = f2bf(val);
          } else {
            if (seg == 0) val *= CEXP;  // fold softmax scale * log2(e) into Q
            qk[((b * 16 + h) * 2048 + s) * 64 + d] = f2bf(val);
          }
        }
      }
  } else {
#pragma unroll
    for (int mi = 0; mi < 4; ++mi)
#pragma unroll
      for (int ni = 0; ni < 4; ++ni) {
        int n = n0 + wn * 64 + ni * 16 + l15;
        float bb = b0[n];
#pragma unroll
        for (int r = 0; r < 4; ++r) {
          int m = m0 + wm * 64 + mi * 16 + quad * 4 + r;
          Of[m * 1024 + n] = acc[mi][ni][r] + bb;
        }
      }
  }
}

// ---------------- flash attention (S^T formulation, no-max softmax) ----------------
// grid: 1024 blocks; swizzled to (bh, qt). 4 waves; wave owns 32 q rows.
// Per kt (64 keys): S^T = K*Q^T (C-layout: key=quad*4+r, q=l15);
// p = exp2(s) (scale pre-folded into Q); P^T packed in regs = PV B-operand
// (V^T global key order pre-permuted to match); O^T += V^T * P^T.
__global__ __launch_bounds__(256) void attn_kernel(const unsigned short* __restrict__ Qg,
                                                   const unsigned short* __restrict__ Kg,
                                                   const unsigned short* __restrict__ Vtg,
                                                   unsigned short* __restrict__ Og) {
  __shared__ __align__(16) unsigned short smem[16384];  // 32 KB
  // [0..8191]: Q tile, later K/V buf1 (K@0, V@4096). [8192..]: K/V buf0.
  const int t = threadIdx.x;
  const int lane = t & 63, wave = t >> 6;
  const int l15 = lane & 15, quad = lane >> 4;
  const int bid = blockIdx.x;
  const int bh = (bid & 7) * 8 + (bid >> 7);  // XCD-affinity: same bh -> same XCD
  const int qt = (bid >> 3) & 15;

  const unsigned short* Qh = Qg + (bh * 2048 + qt * 128) * 64;
  const unsigned short* Kh = Kg + bh * 2048 * 64;
  const unsigned short* Vth = Vtg + bh * 64 * 2048;

  // stage Q (128x64, swizzled)
#pragma unroll
  for (int p = 0; p < 4; ++p) {
    int s = p * 256 + t;
    int row = s >> 3, cc = (s & 7) ^ (row & 7);
    gl_lds16(Qh + row * 64 + cc * 8, (void*)(smem + (p * 256 + wave * 64) * 8));
  }
  __syncthreads();

  const int Xo0 = ((quad ^ (l15 & 7)) * 8);
  const int Xo1 = (((4 + quad) ^ (l15 & 7)) * 8);

  // loop-invariant Q fragments (B-operand: lane=q, elems=d)
  bf16x8 qf[2][2];
#pragma unroll
  for (int qi = 0; qi < 2; ++qi) {
    qf[qi][0] = *(const bf16x8*)&smem[(wave * 32 + qi * 16 + l15) * 64 + Xo0];
    qf[qi][1] = *(const bf16x8*)&smem[(wave * 32 + qi * 16 + l15) * 64 + Xo1];
  }

  // stage K/V tile 0 into buf0
#pragma unroll
  for (int p = 0; p < 2; ++p) {
    int s = p * 256 + t;
    int row = s >> 3, cc = (s & 7) ^ (row & 7);
    gl_lds16(Kh + row * 64 + cc * 8, (void*)(smem + 8192 + (p * 256 + wave * 64) * 8));
    gl_lds16(Vth + row * 2048 + cc * 8, (void*)(smem + 12288 + (p * 256 + wave * 64) * 8));
  }

  f32x4 oacc[4][2];
#pragma unroll
  for (int di = 0; di < 4; ++di)
#pragma unroll
    for (int qi = 0; qi < 2; ++qi) oacc[di][qi] = (f32x4){0.f, 0.f, 0.f, 0.f};
  float lsum[2] = {0.f, 0.f};

  for (int kt = 0; kt < 32; ++kt) {
    __syncthreads();  // buf[kt&1] loads drained; prior compute on buf[(kt+1)&1] done
    if (kt + 1 < 32) {
      const unsigned short* Kn = Kh + (kt + 1) * 64 * 64;
      const unsigned short* Vn = Vth + (kt + 1) * 64;
      unsigned short* Kd = smem + (((kt + 1) & 1) ? 0 : 8192);
      unsigned short* Vd = smem + (((kt + 1) & 1) ? 4096 : 12288);
#pragma unroll
      for (int p = 0; p < 2; ++p) {
        int s = p * 256 + t;
        int row = s >> 3, cc = (s & 7) ^ (row & 7);
        gl_lds16(Kn + row * 64 + cc * 8, (void*)(Kd + (p * 256 + wave * 64) * 8));
        gl_lds16(Vn + row * 2048 + cc * 8, (void*)(Vd + (p * 256 + wave * 64) * 8));
      }
    }
    const unsigned short* Ks = smem + ((kt & 1) ? 0 : 8192);
    const unsigned short* Vs = smem + ((kt & 1) ? 4096 : 12288);

    // S^T = K * Q^T
    f32x4 sacc[4][2];
#pragma unroll
    for (int ki = 0; ki < 4; ++ki)
#pragma unroll
      for (int qi = 0; qi < 2; ++qi) sacc[ki][qi] = (f32x4){0.f, 0.f, 0.f, 0.f};
#pragma unroll
    for (int kc = 0; kc < 2; ++kc) {
      const int Xo = kc ? Xo1 : Xo0;
      bf16x8 kf[4];
#pragma unroll
      for (int ki = 0; ki < 4; ++ki)
        kf[ki] = *(const bf16x8*)&Ks[(ki * 16 + l15) * 64 + Xo];
#pragma unroll
      for (int ki = 0; ki < 4; ++ki)
#pragma unroll
        for (int qi = 0; qi < 2; ++qi)
          sacc[ki][qi] = __builtin_amdgcn_mfma_f32_16x16x32_bf16(kf[ki], qf[qi][kc], sacc[ki][qi], 0, 0, 0);
    }

    // p = 2^s; accumulate row sums per-lane; pack P^T pairs in B-operand order
    i32x4 pk[2][2];
#pragma unroll
    for (int qi = 0; qi < 2; ++qi) {
      float ls = 0.f;
#pragma unroll
      for (int kc = 0; kc < 2; ++kc)
#pragma unroll
        for (int u = 0; u < 2; ++u) {
          int ki = kc * 2 + u;
          float p0 = __builtin_amdgcn_exp2f(sacc[ki][qi][0]);
          float p1 = __builtin_amdgcn_exp2f(sacc[ki][qi][1]);
          float p2 = __builtin_amdgcn_exp2f(sacc[ki][qi][2]);
          float p3 = __builtin_amdgcn_exp2f(sacc[ki][qi][3]);
          ls += (p0 + p1) + (p2 + p3);
          // bf16 round-half-up pack: (hi(a+0x8000)<<16)|hi(b+0x8000)
          pk[qi][kc][u * 2 + 0] =
              (int)__builtin_amdgcn_perm(fbits(p1) + 0x8000u, fbits(p0) + 0x8000u, 0x07060302u);
          pk[qi][kc][u * 2 + 1] =
              (int)__builtin_amdgcn_perm(fbits(p3) + 0x8000u, fbits(p2) + 0x8000u, 0x07060302u);
        }
      lsum[qi] += ls;
    }

    // O^T += V^T * P^T
#pragma unroll
    for (int kc = 0; kc < 2; ++kc) {
      const int Xo = kc ? Xo1 : Xo0;
      bf16x8 vf[4];
#pragma unroll
      for (int di = 0; di < 4; ++di)
        vf[di] = *(const bf16x8*)&Vs[(di * 16 + l15) * 64 + Xo];
#pragma unroll
      for (int di = 0; di < 4; ++di)
#pragma unroll
        for (int qi = 0; qi < 2; ++qi)
          oacc[di][qi] = __builtin_amdgcn_mfma_f32_16x16x32_bf16(
              vf[di], __builtin_bit_cast(bf16x8, pk[qi][kc]), oacc[di][qi], 0, 0, 0);
    }
  }

  // epilogue: O^T/l -> Og[b*2048+q][h*64+d] (bf16). C-layout: d=di*16+quad*4+r, q=qi*16+l15.
  const int b = bh >> 4, h = bh & 15;
#pragma unroll
  for (int qi = 0; qi < 2; ++qi) {
    float l = lsum[qi];
    l += __shfl_xor(l, 16);
    l += __shfl_xor(l, 32);
    float inv = 1.f / l;
    int q = qt * 128 + wave * 32 + qi * 16 + l15;
#pragma unroll
    for (int di = 0; di < 4; ++di) {
      unsigned int lo = (unsigned int)f2bf(oacc[di][qi][0] * inv) |
                        ((unsigned int)f2bf(oacc[di][qi][1] * inv) << 16);
      unsigned int hi = (unsigned int)f2bf(oacc[di][qi][2] * inv) |
                        ((unsigned int)f2bf(oacc[di][qi][3] * inv) << 16);
      uint2 st; st.x = lo; st.y = hi;
      *(uint2*)(Og + ((size_t)(b * 2048 + q) * 1024) + h * 64 + di * 16 + quad * 4) = st;
    }
  }
}

extern "C" void kernel_launch(void* const* d_in, const int* in_sizes, int n_in,
                              void* d_out, int out_size, void* d_ws, size_t ws_size,
                              hipStream_t stream) {
  const float* x  = (const float*)d_in[0];
  const float* wq = (const float*)d_in[1];
  const float* bq = (const float*)d_in[2];
  const float* wk = (const float*)d_in[3];
  const float* bk = (const float*)d_in[4];
  const float* wv = (const float*)d_in[5];
  const float* bv = (const float*)d_in[6];
  const float* wo = (const float*)d_in[7];
  const float* bo = (const float*)d_in[8];
  char* ws = (char*)d_ws;
  unsigned short* Xb    = (unsigned short*)(ws);                      // 16 MB
  unsigned short* Wqkvt = (unsigned short*)(ws + (16ull << 20));      // 6 MB
  unsigned short* Wot   = (unsigned short*)(ws + (22ull << 20));      // 2 MB
  unsigned short* Qg    = (unsigned short*)(ws + (24ull << 20));      // 16 MB
  unsigned short* Kg    = (unsigned short*)(ws + (40ull << 20));      // 16 MB
  unsigned short* Vtg   = (unsigned short*)(ws + (56ull << 20));      // 16 MB
  unsigned short* Og    = (unsigned short*)(ws + (72ull << 20));      // 16 MB

  pack_x_kernel<<<8192, 256, 0, stream>>>(x, Xb);
  pack_w_kernel<<<1024, 256, 0, stream>>>(wq, wk, wv, wo, Wqkvt, Wot);
  gemm_bt_kernel<0><<<dim3(64, 24), 256, 0, stream>>>(Xb, Wqkvt, bq, bk, bv,
                                                      Qg, Kg, Vtg, nullptr);
  attn_kernel<<<1024, 256, 0, stream>>>(Qg, Kg, Vtg, Og);
  gemm_bt_kernel<1><<<dim3(64, 8), 256, 0, stream>>>(Og, Wot, bo, nullptr, nullptr,
                                                     nullptr, nullptr, nullptr,
                                                     (float*)d_out);
}

// Round 3
// 283.471 us; speedup vs baseline: 1.4989x; 1.0326x over previous
//
#include <hip/hip_runtime.h>
#include <cstdint>

// Problem: B=4, S=2048, D_MODEL=1024, H=16, depth=64.
// Pipeline: pack x->bf16 + pack/transpose W->bf16 [N][K] (one launch);
// QKV GEMM (bf16 MFMA, fp32 acc, single-barrier double-buffered K-loop) ->
// Q[bh,s,d] (pre-scaled by log2e/8), K[bh,s,d], Vt[bh,d,s'] key-permuted;
// flash attention (no-max softmax, P stays in registers); out GEMM -> fp32.

typedef __bf16 bf16x8 __attribute__((ext_vector_type(8)));
typedef float f32x4 __attribute__((ext_vector_type(4)));
typedef int i32x4 __attribute__((ext_vector_type(4)));

#define CEXP 0.18033688011112042f  // (1/8) * log2(e), folded into Q

__device__ __forceinline__ unsigned short f2bf(float f) {
  union { float f; unsigned int u; } v; v.f = f;
  unsigned int r = v.u + 0x7FFFu + ((v.u >> 16) & 1u);  // RNE
  return (unsigned short)(r >> 16);
}
__device__ __forceinline__ unsigned int fbits(float f) {
  union { float f; unsigned int u; } v; v.f = f; return v.u;
}

// async global->LDS, 16B per lane. LDS dest = wave-uniform base + lane*16.
__device__ __forceinline__ void gl_lds16(const void* g, void* l) {
  __builtin_amdgcn_global_load_lds(
      (const __attribute__((address_space(1))) void*)(unsigned long long)g,
      (__attribute__((address_space(3))) void*)(unsigned int)(unsigned long long)l,
      16, 0, 0);
}

// ---------------- pack x (fp32 -> bf16) + pack/transpose weights ----------------
__global__ __launch_bounds__(256) void pack_all_kernel(const float* __restrict__ x,
                                                       const float* __restrict__ wq,
                                                       const float* __restrict__ wk,
                                                       const float* __restrict__ wv,
                                                       const float* __restrict__ wo,
                                                       unsigned short* __restrict__ xb,
                                                       unsigned short* __restrict__ wqkvt,
                                                       unsigned short* __restrict__ wot) {
  int bid = blockIdx.x;
  if (bid < 8192) {  // pack x
    int i = (bid * 256 + threadIdx.x) * 4;
    float4 v = *(const float4*)(x + i);
    unsigned int lo = (unsigned int)f2bf(v.x) | ((unsigned int)f2bf(v.y) << 16);
    unsigned int hi = (unsigned int)f2bf(v.z) | ((unsigned int)f2bf(v.w) << 16);
    uint2 st; st.x = lo; st.y = hi;
    *(uint2*)(xb + i) = st;
    return;
  }
  // pack + transpose weights: Wt[n][k] = w[k][n]
  __shared__ unsigned short T[64 * 66];  // +2 pad: conflict-free
  bid -= 8192;
  int mat = bid >> 8;                    // 0..3 = wq,wk,wv,wo
  int tile = bid & 255;
  int tk = tile >> 4, tn = tile & 15;    // 64x64 tiles
  const float* W = (mat == 0) ? wq : (mat == 1) ? wk : (mat == 2) ? wv : wo;
  int t = threadIdx.x;
#pragma unroll
  for (int p = 0; p < 16; ++p) {
    int e = p * 256 + t;
    int r = e >> 6, c = e & 63;
    T[c * 66 + r] = f2bf(W[(tk * 64 + r) * 1024 + tn * 64 + c]);
  }
  __syncthreads();
  unsigned short* dst = (mat < 3) ? (wqkvt + mat * 1024 * 1024) : wot;
#pragma unroll
  for (int p = 0; p < 16; ++p) {
    int e = p * 256 + t;
    int nn = e >> 6, kk = e & 63;
    dst[(tn * 64 + nn) * 1024 + tk * 64 + kk] = T[nn * 66 + kk];
  }
}

// stage one 128x64 A-tile and 128x64 B-tile (swizzled) via global_load_lds
__device__ __forceinline__ void stage_tile(const unsigned short* __restrict__ Ag,
                                           const unsigned short* __restrict__ Bg,
                                           unsigned short* As, unsigned short* Bs,
                                           int t, int wave) {
#pragma unroll
  for (int p = 0; p < 4; ++p) {
    int s = p * 256 + t;
    int row = s >> 3;
    int cc = (s & 7) ^ (row & 7);
    gl_lds16(Ag + row * 1024 + cc * 8, (void*)(As + (p * 256 + wave * 64) * 8));
    gl_lds16(Bg + row * 1024 + cc * 8, (void*)(Bs + (p * 256 + wave * 64) * 8));
  }
}

// ---------------- GEMM: C[M][N] = A[M][1024] * Bt[N][1024]^T ----------------
// Single-barrier double-buffered K-loop (prefetch flies during compute).
// MODE 0: QKV epilogue (bias + scatter bf16 to Q/K/Vt; Q pre-scaled by CEXP;
//         Vt key order permuted within 64-blocks).  MODE 1: fp32 out + bias.
template <int MODE>
__global__ __launch_bounds__(256) void gemm_bt_kernel(
    const unsigned short* __restrict__ A, const unsigned short* __restrict__ Bt,
    const float* __restrict__ b0, const float* __restrict__ b1, const float* __restrict__ b2,
    unsigned short* __restrict__ Qg, unsigned short* __restrict__ Kg,
    unsigned short* __restrict__ Vtg, float* __restrict__ Of) {
  __shared__ __align__(16) unsigned short S[32768];  // 64KB: [buf][A 8192 | B 8192]
  const int t = threadIdx.x;
  const int lane = t & 63, wave = t >> 6;
  const int l15 = lane & 15, quad = lane >> 4;
  const int wm = wave & 1, wn = wave >> 1;
  const int m0 = blockIdx.x * 128, n0 = blockIdx.y * 128;
  const unsigned short* Ab = A + (size_t)m0 * 1024;
  const unsigned short* Bb = Bt + (size_t)n0 * 1024;

  f32x4 acc[4][4];
#pragma unroll
  for (int i = 0; i < 4; ++i)
#pragma unroll
    for (int j = 0; j < 4; ++j) acc[i][j] = (f32x4){0.f, 0.f, 0.f, 0.f};

  const int Xo0 = ((quad ^ (l15 & 7)) * 8);
  const int Xo1 = (((4 + quad) ^ (l15 & 7)) * 8);

  stage_tile(Ab, Bb, S, S + 8192, t, wave);  // tile 0 -> buf 0

  for (int k0 = 0; k0 < 1024; k0 += 64) {
    const int buf = (k0 >> 6) & 1;
    unsigned short* Sc = S + buf * 16384;
    __syncthreads();  // drains buf's loads (issued one full iteration ago)
    if (k0 < 1024 - 64) {
      unsigned short* Sn = S + (buf ^ 1) * 16384;
      stage_tile(Ab + k0 + 64, Bb + k0 + 64, Sn, Sn + 8192, t, wave);
    }
#pragma unroll
    for (int kc = 0; kc < 2; ++kc) {
      const int Xo = kc ? Xo1 : Xo0;
      bf16x8 af[4], bfr[4];
#pragma unroll
      for (int mi = 0; mi < 4; ++mi)
        af[mi] = *(const bf16x8*)&Sc[(wm * 64 + mi * 16 + l15) * 64 + Xo];
#pragma unroll
      for (int ni = 0; ni < 4; ++ni)
        bfr[ni] = *(const bf16x8*)&Sc[8192 + (wn * 64 + ni * 16 + l15) * 64 + Xo];
#pragma unroll
      for (int mi = 0; mi < 4; ++mi)
#pragma unroll
        for (int ni = 0; ni < 4; ++ni)
          acc[mi][ni] = __builtin_amdgcn_mfma_f32_16x16x32_bf16(af[mi], bfr[ni], acc[mi][ni], 0, 0, 0);
    }
  }

  if (MODE == 0) {
    const int seg = blockIdx.y >> 3;  // 0=Q,1=K,2=V
    const float* bias = (seg == 0) ? b0 : (seg == 1) ? b1 : b2;
    unsigned short* qk = (seg == 0) ? Qg : Kg;
#pragma unroll
    for (int mi = 0; mi < 4; ++mi)
#pragma unroll
      for (int ni = 0; ni < 4; ++ni) {
        int n = n0 + wn * 64 + ni * 16 + l15;
        int nn = n & 1023;
        float bb = bias[nn];
        int h = nn >> 6, d = nn & 63;
#pragma unroll
        for (int r = 0; r < 4; ++r) {
          int m = m0 + wm * 64 + mi * 16 + quad * 4 + r;
          int b = m >> 11, s = m & 2047;
          float val = acc[mi][ni][r] + bb;
          if (seg == 2) {
            // permute key order within 64-blocks so attn's P-register order
            // matches V^T's staged order: pos = kc<<5 | q<<3 | u<<2 | r
            int sp = (s & ~63) | (s & 32) | ((s & 12) << 1) | ((s & 16) >> 2) | (s & 3);
            Vtg[((b * 16 + h) * 64 + d) * 2048 + sp] = f2bf(val);
          } else {
            if (seg == 0) val *= CEXP;  // fold softmax scale * log2(e) into Q
            qk[((b * 16 + h) * 2048 + s) * 64 + d] = f2bf(val);
          }
        }
      }
  } else {
#pragma unroll
    for (int mi = 0; mi < 4; ++mi)
#pragma unroll
      for (int ni = 0; ni < 4; ++ni) {
        int n = n0 + wn * 64 + ni * 16 + l15;
        float bb = b0[n];
#pragma unroll
        for (int r = 0; r < 4; ++r) {
          int m = m0 + wm * 64 + mi * 16 + quad * 4 + r;
          Of[m * 1024 + n] = acc[mi][ni][r] + bb;
        }
      }
  }
}

// ---------------- flash attention (S^T formulation, no-max softmax) ----------------
// grid: 1024 blocks; swizzled to (bh, qt). 4 waves; wave owns 32 q rows.
// Per kt (64 keys): S^T = K*Q^T (C-layout: key=quad*4+r, q=l15);
// p = exp2(s) (scale pre-folded into Q); P^T packed in regs = PV B-operand
// (V^T global key order pre-permuted to match); O^T += V^T * P^T.
__global__ __launch_bounds__(256) void attn_kernel(const unsigned short* __restrict__ Qg,
                                                   const unsigned short* __restrict__ Kg,
                                                   const unsigned short* __restrict__ Vtg,
                                                   unsigned short* __restrict__ Og) {
  __shared__ __align__(16) unsigned short smem[16384];  // 32 KB
  // [0..8191]: Q tile, later K/V buf1 (K@0, V@4096). [8192..]: K/V buf0.
  const int t = threadIdx.x;
  const int lane = t & 63, wave = t >> 6;
  const int l15 = lane & 15, quad = lane >> 4;
  const int bid = blockIdx.x;
  const int bh = (bid & 7) * 8 + (bid >> 7);  // XCD-affinity: same bh -> same XCD
  const int qt = (bid >> 3) & 15;

  const unsigned short* Qh = Qg + (bh * 2048 + qt * 128) * 64;
  const unsigned short* Kh = Kg + bh * 2048 * 64;
  const unsigned short* Vth = Vtg + bh * 64 * 2048;

  // stage Q (128x64, swizzled)
#pragma unroll
  for (int p = 0; p < 4; ++p) {
    int s = p * 256 + t;
    int row = s >> 3, cc = (s & 7) ^ (row & 7);
    gl_lds16(Qh + row * 64 + cc * 8, (void*)(smem + (p * 256 + wave * 64) * 8));
  }
  __syncthreads();

  const int Xo0 = ((quad ^ (l15 & 7)) * 8);
  const int Xo1 = (((4 + quad) ^ (l15 & 7)) * 8);

  // loop-invariant Q fragments (B-operand: lane=q, elems=d)
  bf16x8 qf[2][2];
#pragma unroll
  for (int qi = 0; qi < 2; ++qi) {
    qf[qi][0] = *(const bf16x8*)&smem[(wave * 32 + qi * 16 + l15) * 64 + Xo0];
    qf[qi][1] = *(const bf16x8*)&smem[(wave * 32 + qi * 16 + l15) * 64 + Xo1];
  }

  // stage K/V tile 0 into buf0
#pragma unroll
  for (int p = 0; p < 2; ++p) {
    int s = p * 256 + t;
    int row = s >> 3, cc = (s & 7) ^ (row & 7);
    gl_lds16(Kh + row * 64 + cc * 8, (void*)(smem + 8192 + (p * 256 + wave * 64) * 8));
    gl_lds16(Vth + row * 2048 + cc * 8, (void*)(smem + 12288 + (p * 256 + wave * 64) * 8));
  }

  f32x4 oacc[4][2];
#pragma unroll
  for (int di = 0; di < 4; ++di)
#pragma unroll
    for (int qi = 0; qi < 2; ++qi) oacc[di][qi] = (f32x4){0.f, 0.f, 0.f, 0.f};
  float lsum[2] = {0.f, 0.f};

  for (int kt = 0; kt < 32; ++kt) {
    __syncthreads();  // buf[kt&1] loads drained; prior compute on buf[(kt+1)&1] done
    if (kt + 1 < 32) {
      const unsigned short* Kn = Kh + (kt + 1) * 64 * 64;
      const unsigned short* Vn = Vth + (kt + 1) * 64;
      unsigned short* Kd = smem + (((kt + 1) & 1) ? 0 : 8192);
      unsigned short* Vd = smem + (((kt + 1) & 1) ? 4096 : 12288);
#pragma unroll
      for (int p = 0; p < 2; ++p) {
        int s = p * 256 + t;
        int row = s >> 3, cc = (s & 7) ^ (row & 7);
        gl_lds16(Kn + row * 64 + cc * 8, (void*)(Kd + (p * 256 + wave * 64) * 8));
        gl_lds16(Vn + row * 2048 + cc * 8, (void*)(Vd + (p * 256 + wave * 64) * 8));
      }
    }
    const unsigned short* Ks = smem + ((kt & 1) ? 0 : 8192);
    const unsigned short* Vs = smem + ((kt & 1) ? 4096 : 12288);

    // S^T = K * Q^T
    f32x4 sacc[4][2];
#pragma unroll
    for (int ki = 0; ki < 4; ++ki)
#pragma unroll
      for (int qi = 0; qi < 2; ++qi) sacc[ki][qi] = (f32x4){0.f, 0.f, 0.f, 0.f};
#pragma unroll
    for (int kc = 0; kc < 2; ++kc) {
      const int Xo = kc ? Xo1 : Xo0;
      bf16x8 kf[4];
#pragma unroll
      for (int ki = 0; ki < 4; ++ki)
        kf[ki] = *(const bf16x8*)&Ks[(ki * 16 + l15) * 64 + Xo];
#pragma unroll
      for (int ki = 0; ki < 4; ++ki)
#pragma unroll
        for (int qi = 0; qi < 2; ++qi)
          sacc[ki][qi] = __builtin_amdgcn_mfma_f32_16x16x32_bf16(kf[ki], qf[qi][kc], sacc[ki][qi], 0, 0, 0);
    }

    // p = 2^s; accumulate row sums per-lane; pack P^T pairs in B-operand order
    i32x4 pk[2][2];
#pragma unroll
    for (int qi = 0; qi < 2; ++qi) {
      float ls = 0.f;
#pragma unroll
      for (int kc = 0; kc < 2; ++kc)
#pragma unroll
        for (int u = 0; u < 2; ++u) {
          int ki = kc * 2 + u;
          float p0 = __builtin_amdgcn_exp2f(sacc[ki][qi][0]);
          float p1 = __builtin_amdgcn_exp2f(sacc[ki][qi][1]);
          float p2 = __builtin_amdgcn_exp2f(sacc[ki][qi][2]);
          float p3 = __builtin_amdgcn_exp2f(sacc[ki][qi][3]);
          ls += (p0 + p1) + (p2 + p3);
          // bf16 round-half-up pack: (hi(a+0x8000)<<16)|hi(b+0x8000)
          pk[qi][kc][u * 2 + 0] =
              (int)__builtin_amdgcn_perm(fbits(p1) + 0x8000u, fbits(p0) + 0x8000u, 0x07060302u);
          pk[qi][kc][u * 2 + 1] =
              (int)__builtin_amdgcn_perm(fbits(p3) + 0x8000u, fbits(p2) + 0x8000u, 0x07060302u);
        }
      lsum[qi] += ls;
    }

    // O^T += V^T * P^T
#pragma unroll
    for (int kc = 0; kc < 2; ++kc) {
      const int Xo = kc ? Xo1 : Xo0;
      bf16x8 vf[4];
#pragma unroll
      for (int di = 0; di < 4; ++di)
        vf[di] = *(const bf16x8*)&Vs[(di * 16 + l15) * 64 + Xo];
#pragma unroll
      for (int di = 0; di < 4; ++di)
#pragma unroll
        for (int qi = 0; qi < 2; ++qi)
          oacc[di][qi] = __builtin_amdgcn_mfma_f32_16x16x32_bf16(
              vf[di], __builtin_bit_cast(bf16x8, pk[qi][kc]), oacc[di][qi], 0, 0, 0);
    }
  }

  // epilogue: O^T/l -> Og[b*2048+q][h*64+d] (bf16). C-layout: d=di*16+quad*4+r, q=qi*16+l15.
  const int b = bh >> 4, h = bh & 15;
#pragma unroll
  for (int qi = 0; qi < 2; ++qi) {
    float l = lsum[qi];
    l += __shfl_xor(l, 16);
    l += __shfl_xor(l, 32);
    float inv = 1.f / l;
    int q = qt * 128 + wave * 32 + qi * 16 + l15;
#pragma unroll
    for (int di = 0; di < 4; ++di) {
      unsigned int lo = (unsigned int)f2bf(oacc[di][qi][0] * inv) |
                        ((unsigned int)f2bf(oacc[di][qi][1] * inv) << 16);
      unsigned int hi = (unsigned int)f2bf(oacc[di][qi][2] * inv) |
                        ((unsigned int)f2bf(oacc[di][qi][3] * inv) << 16);
      uint2 st; st.x = lo; st.y = hi;
      *(uint2*)(Og + ((size_t)(b * 2048 + q) * 1024) + h * 64 + di * 16 + quad * 4) = st;
    }
  }
}

extern "C" void kernel_launch(void* const* d_in, const int* in_sizes, int n_in,
                              void* d_out, int out_size, void* d_ws, size_t ws_size,
                              hipStream_t stream) {
  const float* x  = (const float*)d_in[0];
  const float* wq = (const float*)d_in[1];
  const float* bq = (const float*)d_in[2];
  const float* wk = (const float*)d_in[3];
  const float* bk = (const float*)d_in[4];
  const float* wv = (const float*)d_in[5];
  const float* bv = (const float*)d_in[6];
  const float* wo = (const float*)d_in[7];
  const float* bo = (const float*)d_in[8];
  char* ws = (char*)d_ws;
  unsigned short* Xb    = (unsigned short*)(ws);                      // 16 MB
  unsigned short* Wqkvt = (unsigned short*)(ws + (16ull << 20));      // 6 MB
  unsigned short* Wot   = (unsigned short*)(ws + (22ull << 20));      // 2 MB
  unsigned short* Qg    = (unsigned short*)(ws + (24ull << 20));      // 16 MB
  unsigned short* Kg    = (unsigned short*)(ws + (40ull << 20));      // 16 MB
  unsigned short* Vtg   = (unsigned short*)(ws + (56ull << 20));      // 16 MB
  unsigned short* Og    = (unsigned short*)(ws + (72ull << 20));      // 16 MB

  pack_all_kernel<<<9216, 256, 0, stream>>>(x, wq, wk, wv, wo, Xb, Wqkvt, Wot);
  gemm_bt_kernel<0><<<dim3(64, 24), 256, 0, stream>>>(Xb, Wqkvt, bq, bk, bv,
                                                      Qg, Kg, Vtg, nullptr);
  attn_kernel<<<1024, 256, 0, stream>>>(Qg, Kg, Vtg, Og);
  gemm_bt_kernel<1><<<dim3(64, 8), 256, 0, stream>>>(Og, Wot, bo, nullptr, nullptr,
                                                     nullptr, nullptr, nullptr,
                                                     (float*)d_out);
}